// Round 2
// baseline (65.372 us; speedup 1.0000x reference)
//
#include <hip/hip_runtime.h>

// LambdaLoss: B=4096 lists, L=128 items.
// per list: sum over pairs rel_i > rel_j of |rd| * softplus(-(p_i - p_j)),
// divided by valid-pair count; output = mean over lists with >=1 valid pair.
//
// Decomposition (unchanged from prior round): with E_k = exp2(p_k*log2e),
// y_k = p_k*log2e:
//   softplus(-(p_w - p_l)) = ln2 * (log2(E_i + E_j) - y_w)
// winner-y part is separable via the relevance histogram:
//   sum_pairs |rd|*y_w = sum_i y_i * W_i,  W_i = sum_v c_v * relu(r_i - v)
// so the per-pair loop needs only (E_j, r_j) -> ONE ds_read_b64 (float2)
// and ~4 VALU ops (sub, add, v_log, fma).
//
// This round (R7, re-run — prior bench died to container infra failure):
//  - 2 lists per block: 2048 blocks x 256 thr = exactly 8 blk/CU x 4 waves
//    = 32 waves/CU in ONE occupancy round (was 4096 blocks -> 2 rounds).
//    Halves per-list barrier/reduction/launch overhead; A/B accumulator
//    chains double ILP under the v_log latency.
//  - histogram via __ballot/popcll per wave (waves 0-1) instead of LDS
//    atomicAdd: removes ~26-way same-address atomic serialization AND one
//    __syncthreads (staging barrier now covers hist too).
//  - per-pair math and summation order bit-identical to prior kernel.
// Kernel 2: single block, coalesced float4 reduction of 2048 float2.

#define LB 4096
#define LPB 2            // lists per block
#define NBLK (LB / LPB)  // 2048
#define LLEN 128
#define MIR 192          // mirrored length: max index 129 + 62 = 191

#define EXP2F(x) __builtin_amdgcn_exp2f(x)   // v_exp_f32 (2^x)
#define LOG2F(x) __builtin_amdgcn_logf(x)    // v_log_f32 (log2)

__global__ __launch_bounds__(256) void lambda_pairs_kernel(
    const float* __restrict__ pred, const float* __restrict__ rel,
    float2* __restrict__ per2) {
  __shared__ float2 sA[MIR], sB[MIR];   // (E, r), mirrored, per list
  __shared__ int histA[2][5], histB[2][5];   // per-wave ballot counts
  __shared__ float wsumA[4], wsumB[4];

  const int t = threadIdx.x;
  const int b = blockIdx.x;            // handles lists 2b, 2b+1
  const int i = t & (LLEN - 1);

  constexpr float LOG2E = 1.4426950408889634f;
  constexpr float LN2   = 0.6931471805599453f;

  // stage: every thread computes its row's (E, r) for both lists;
  // t in [128,192) mirrors rows 0..63 (i = t & 127).
  const int baseA = (2 * b) * LLEN;
  const float pA = pred[baseA + i];
  const float rA = rel[baseA + i];
  const float pB = pred[baseA + LLEN + i];
  const float rB = rel[baseA + LLEN + i];
  const float yA = pA * LOG2E, yB = pB * LOG2E;
  const float EA = EXP2F(yA),  EB = EXP2F(yB);

  if (t < MIR) {
    sA[t] = make_float2(EA, rA);
    sB[t] = make_float2(EB, rB);
  }

  // histogram via per-wave ballots (waves 0,1 cover rows 0..127; all 64
  // lanes of each wave are active inside the t<128 branch).
  if (t < 128) {
    const int w = t >> 6;
#pragma unroll
    for (int v = 0; v < 5; ++v) {
      unsigned long long mA = __ballot(rA == (float)v);
      unsigned long long mB = __ballot(rB == (float)v);
      if ((t & 63) == 0) {
        histA[w][v] = __popcll(mA);
        histB[w][v] = __popcll(mB);
      }
    }
  }
  __syncthreads();   // covers sA/sB and hist

  // thread half selects odd (d=1,3,..,63) or even (d=2,4,..,64) offsets
  const int j0 = i + 1 + (t >> 7);   // max addr: 129 + 62 = 191
  float accA = 0.f, accB = 0.f;

#pragma unroll 8
  for (int k = 0; k < 31; ++k) {
    float2 vA = sA[j0 + 2 * k];
    float2 vB = sB[j0 + 2 * k];
    accA = fmaf(fabsf(rA - vA.y), LOG2F(EA + vA.x), accA);  // |rd|=0 ties
    accB = fmaf(fabsf(rB - vB.y), LOG2F(EB + vB.x), accB);
  }
  { // tail: d=63 (lower half, all i) or d=64 (upper half, only i<64)
    float2 vA = sA[j0 + 62];
    float2 vB = sB[j0 + 62];
    const bool on = (t < 128) || (i < 64);
    float wA = on ? fabsf(rA - vA.y) : 0.f;
    float wB = on ? fabsf(rB - vB.y) : 0.f;
    accA = fmaf(wA, LOG2F(EA + vA.x), accA);
    accB = fmaf(wB, LOG2F(EB + vB.x), accB);
  }

  // per-row winner-y correction: acc -= y_i * W_i (one thread per row)
  if (t < LLEN) {
    float WA = 0.f, WB = 0.f;
#pragma unroll
    for (int v = 0; v < 5; ++v) {
      float hA = (float)(histA[0][v] + histA[1][v]);
      float hB = (float)(histB[0][v] + histB[1][v]);
      WA = fmaf(hA, fmaxf(rA - (float)v, 0.f), WA);
      WB = fmaf(hB, fmaxf(rB - (float)v, 0.f), WB);
    }
    accA = fmaf(-yA, WA, accA);
    accB = fmaf(-yB, WB, accB);
  }

  // wave (64-lane) shuffle reduction, then cross-wave via LDS
  for (int off = 32; off > 0; off >>= 1) {
    accA += __shfl_down(accA, off, 64);
    accB += __shfl_down(accB, off, 64);
  }
  if ((t & 63) == 0) { wsumA[t >> 6] = accA; wsumB[t >> 6] = accB; }
  __syncthreads();
  if (t == 0) {
    float ssA = (wsumA[0] + wsumA[1]) + (wsumA[2] + wsumA[3]);
    float ssB = (wsumB[0] + wsumB[1]) + (wsumB[2] + wsumB[3]);
    int sameA = 0, sameB = 0;
#pragma unroll
    for (int v = 0; v < 5; ++v) {
      int hA = histA[0][v] + histA[1][v];
      int hB = histB[0][v] + histB[1][v];
      sameA += hA * (hA - 1) / 2;
      sameB += hB * (hB - 1) / 2;
    }
    const int tot = LLEN * (LLEN - 1) / 2;
    const int cA = tot - sameA, cB = tot - sameB;
    per2[2 * b] = make_float2((cA > 0) ? (LN2 * ssA) / (float)cA : 0.f,
                              (cA > 0) ? 1.f : 0.f);
    per2[2 * b + 1] = make_float2((cB > 0) ? (LN2 * ssB) / (float)cB : 0.f,
                                  (cB > 0) ? 1.f : 0.f);
  }
}

__global__ __launch_bounds__(256) void lambda_finalize_kernel(
    const float2* __restrict__ per2, float* __restrict__ out) {
  __shared__ float wsum[4], wcnt[4];
  const int t = threadIdx.x;
  const float4* v = (const float4*)per2;   // 2048 float2 = 1024 float4
  float s = 0.f, n = 0.f;
#pragma unroll
  for (int idx = t; idx < 1024; idx += 256) {
    float4 q = v[idx];
    s += q.x + q.z;
    n += q.y + q.w;
  }
  for (int off = 32; off > 0; off >>= 1) {
    s += __shfl_down(s, off, 64);
    n += __shfl_down(n, off, 64);
  }
  if ((t & 63) == 0) { wsum[t >> 6] = s; wcnt[t >> 6] = n; }
  __syncthreads();
  if (t == 0) {
    float ts = (wsum[0] + wsum[1]) + (wsum[2] + wsum[3]);
    float tn = (wcnt[0] + wcnt[1]) + (wcnt[2] + wcnt[3]);
    out[0] = (tn > 0.f) ? ts / tn : 0.f;
  }
}

extern "C" void kernel_launch(void* const* d_in, const int* in_sizes, int n_in,
                              void* d_out, int out_size, void* d_ws, size_t ws_size,
                              hipStream_t stream) {
  const float* pred = (const float*)d_in[0];
  const float* rel  = (const float*)d_in[1];
  float* out   = (float*)d_out;
  float2* per2 = (float2*)d_ws;   // [2048] (ratio, valid)

  lambda_pairs_kernel<<<dim3(NBLK), dim3(256), 0, stream>>>(pred, rel, per2);
  lambda_finalize_kernel<<<dim3(1), dim3(256), 0, stream>>>(per2, out);
}